// Round 6
// baseline (323.631 us; speedup 1.0000x reference)
//
#include <hip/hip_runtime.h>
#include <math.h>

// Problem constants
#define T      2048
#define HIDDEN 2048
#define NH     32
#define NKV    4
#define D      128
#define WINDOW 512
#define QKVW   ((NH + 2 * NKV) * D)   // 5120
#define ODIM   (NH * D)               // 4096
#define EPS    1e-6f
#define SCALE  0.08838834764831845f   // D^-0.5
#define PSTR   68                     // P-slab stride (validated R5, conflict-free)
#define ESTR   136                    // epilogue exchange slab row stride (fp16)
#define QMUL   ((float)(0.08838834764831845 * 1.4426950408889634))
#define MLOG2E 5.7707801635558536f    // 4.0*log2(e); |score|<=11.3 (Cauchy-Schwarz)

typedef _Float16 f16x8 __attribute__((ext_vector_type(8)));
typedef float    f32x4 __attribute__((ext_vector_type(4)));

// ---------------------------------------------------------------------------
// Packed fragment format (validated R2-R5):
// chunk c = q*16 + o (q=c>>4, o=c&15), chunk = 8 k-consecutive f16 at outer o.
// A-operand: lane holds A[m=lane&15][k=(lane>>4)*8+j]
// B-operand: lane holds B[k=(lane>>4)*8+j][n=lane&15]
// ---------------------------------------------------------------------------

__global__ __launch_bounds__(256)
void pack_a(const float* __restrict__ A, _Float16* __restrict__ out,
            int M, int K) {
  const int cid = blockIdx.x * 256 + threadIdx.x;
  const int c = cid & 63;
  const int tile = cid >> 6;
  const int mtg = tile % (M >> 4);
  const int kt = tile / (M >> 4);
  const int m = c & 15, q = c >> 4;
  const float* src = A + (size_t)(mtg * 16 + m) * K + kt * 32 + q * 8;
  const float4 a = *(const float4*)src;
  const float4 b = *(const float4*)(src + 4);
  f16x8 h;
  h[0] = (_Float16)a.x; h[1] = (_Float16)a.y; h[2] = (_Float16)a.z; h[3] = (_Float16)a.w;
  h[4] = (_Float16)b.x; h[5] = (_Float16)b.y; h[6] = (_Float16)b.z; h[7] = (_Float16)b.w;
  *(f16x8*)(out + (size_t)cid * 8) = h;
}

__global__ __launch_bounds__(256)
void pack_b(const float* __restrict__ B, _Float16* __restrict__ out,
            int K, int N) {
  const int cid = blockIdx.x * 256 + threadIdx.x;
  const int c = cid & 63;
  const int tile = cid >> 6;
  const int ntg = tile % (N >> 4);
  const int kt = tile / (N >> 4);
  const int n = c & 15, q = c >> 4;
  const float* src = B + (size_t)(kt * 32 + q * 8) * N + ntg * 16 + n;
  f16x8 h;
#pragma unroll
  for (int j = 0; j < 8; ++j) h[j] = (_Float16)src[(size_t)j * N];
  *(f16x8*)(out + (size_t)cid * 8) = h;
}

__device__ __forceinline__ void gl2lds16(const void* g, void* l) {
  __builtin_amdgcn_global_load_lds((const __attribute__((address_space(1))) void*)g,
                                   (__attribute__((address_space(3))) void*)l,
                                   16, 0, 0);
}

// ---------------------------------------------------------------------------
// gemm1 fused: qkv = hidden @ w_qkv, with RMSNorm+RoPE+fragment-pack epilogue.
// BN=128 == D, so blockIdx.x selects exactly one head:
//   bx<32: q head -> Qpk ; bx 32..35: k head -> Kpk ; bx 36..39: v -> Vpk.
// No fp32 qkv intermediate ever touches HBM.
// ---------------------------------------------------------------------------
__global__ __launch_bounds__(256)
void gemm_qkv(const _Float16* __restrict__ Apk, const _Float16* __restrict__ Bpk,
              const float* __restrict__ qnw, const float* __restrict__ knw,
              const float* __restrict__ cosT, const float* __restrict__ sinT,
              _Float16* __restrict__ Qpk, _Float16* __restrict__ Kpk,
              _Float16* __restrict__ Vpk) {
  constexpr int AT = 8, BT = 8, RT = 4, CT = 4;
  constexpr int NKT = HIDDEN / 32;     // 64
  // union: staging (32 KB) / epilogue exchange 128x136 f16 (34 KB) + sums (1 KB)
  __shared__ _Float16 SM[17920];
  _Float16* As = SM;                   // 2*8*512 f16
  _Float16* Bs = SM + 8192;

  const int tid = threadIdx.x;
  const int lane = tid & 63;
  const int wv = tid >> 6;
  const int wr = wv & 1, wc = wv >> 1;
  const int l15 = lane & 15;
  const int l4 = lane >> 4;
  const int bx = blockIdx.x, by = blockIdx.y;

  f32x4 acc[RT][CT];
#pragma unroll
  for (int i = 0; i < RT; ++i)
#pragma unroll
    for (int j = 0; j < CT; ++j) acc[i][j] = (f32x4)0.f;

  const size_t Astep = (size_t)(T >> 4) * 1024;
  const size_t Bstep = (size_t)(QKVW >> 4) * 1024;
  const char* Ag = (const char*)Apk + (size_t)(by * AT) * 1024 + lane * 16;
  const char* Bg = (const char*)Bpk + (size_t)(bx * BT) * 1024 + lane * 16;

  for (int kt2 = 0; kt2 < NKT; kt2 += 2) {
    const char* a0 = Ag + (size_t)kt2 * Astep;
    const char* b0 = Bg + (size_t)kt2 * Bstep;
#pragma unroll
    for (int t = wv; t < 2 * (AT + BT); t += 4) {
      const int half = t >= (AT + BT);
      const int tt = half ? t - (AT + BT) : t;
      if (tt < AT)
        gl2lds16(a0 + half * Astep + (size_t)tt * 1024,
                 (char*)As + (half * AT + tt) * 1024);
      else
        gl2lds16(b0 + half * Bstep + (size_t)(tt - AT) * 1024,
                 (char*)Bs + (half * BT + (tt - AT)) * 1024);
    }
    __syncthreads();
#pragma unroll
    for (int h2 = 0; h2 < 2; ++h2) {
      f16x8 af[RT], bf[CT];
#pragma unroll
      for (int i = 0; i < RT; ++i)
        af[i] = *(const f16x8*)((const char*)As + (h2 * AT + wr * RT + i) * 1024 + lane * 16);
#pragma unroll
      for (int j = 0; j < CT; ++j)
        bf[j] = *(const f16x8*)((const char*)Bs + (h2 * BT + wc * CT + j) * 1024 + lane * 16);
#pragma unroll
      for (int i = 0; i < RT; ++i)
#pragma unroll
        for (int j = 0; j < CT; ++j)
          acc[i][j] = __builtin_amdgcn_mfma_f32_16x16x32_f16(af[i], bf[j], acc[i][j], 0, 0, 0);
    }
    __syncthreads();
  }

  // ---- fused epilogue ----
  // acc[i][j][r] holds C[row][col]: row = wr*64+i*16+l4*4+r, col = wc*64+j*16+l15
  _Float16* ex = SM;                   // 128 x ESTR fp16 slab
  float* sums = (float*)(SM + 17408);  // [2][128]

  if (bx < NH + NKV) {
    // ---- q/k head: RMSNorm + RoPE + pack to Qpk/Kpk ----
    const bool isq = bx < NH;
    const float* w = isq ? qnw : knw;
    const float omul = isq ? QMUL : 1.0f;

    // per-row sum of squares (partial over this wave's 64 cols)
#pragma unroll
    for (int i = 0; i < RT; ++i)
#pragma unroll
      for (int r = 0; r < 4; ++r) {
        float s = acc[i][0][r] * acc[i][0][r] + acc[i][1][r] * acc[i][1][r]
                + acc[i][2][r] * acc[i][2][r] + acc[i][3][r] * acc[i][3][r];
        s += __shfl_xor(s, 1); s += __shfl_xor(s, 2);
        s += __shfl_xor(s, 4); s += __shfl_xor(s, 8);
        if (l15 == 0) sums[wc * 128 + wr * 64 + i * 16 + l4 * 4 + r] = s;
      }
    __syncthreads();

    // normalize (in place) and publish fp16 copy for the RoPE partner wave
    float wcol[4];
#pragma unroll
    for (int j = 0; j < 4; ++j) wcol[j] = w[wc * 64 + j * 16 + l15];
#pragma unroll
    for (int i = 0; i < RT; ++i)
#pragma unroll
      for (int r = 0; r < 4; ++r) {
        const int row = wr * 64 + i * 16 + l4 * 4 + r;
        const float rn = 1.0f / sqrtf((sums[row] + sums[128 + row]) * (1.0f / D) + EPS);
#pragma unroll
        for (int j = 0; j < 4; ++j) {
          acc[i][j][r] *= rn * wcol[j];
          ex[row * ESTR + wc * 64 + j * 16 + l15] = (_Float16)acc[i][j][r];
        }
      }
    __syncthreads();

    // RoPE: partner value lives at col^64 (the other wc wave)
    const float sgn = (wc == 0) ? -1.f : 1.f;
    const int poff = wc ? 0 : 64;
#pragma unroll
    for (int i = 0; i < RT; ++i)
#pragma unroll
      for (int r = 0; r < 4; ++r) {
        const int row = wr * 64 + i * 16 + l4 * 4 + r;
        const int t = by * 128 + row;
#pragma unroll
        for (int j = 0; j < 4; ++j) {
          const int jc = j * 16 + l15;
          const float c = cosT[t * 64 + jc];
          const float s = sinT[t * 64 + jc];
          const float pr = (float)ex[row * ESTR + jc + poff];
          acc[i][j][r] = acc[i][j][r] * c + sgn * pr * s;
        }
      }
    __syncthreads();  // all partner reads done before overwriting ex

    // write rotated (x omul) back, then re-read in A-frag order
#pragma unroll
    for (int i = 0; i < RT; ++i)
#pragma unroll
      for (int r = 0; r < 4; ++r) {
        const int row = wr * 64 + i * 16 + l4 * 4 + r;
#pragma unroll
        for (int j = 0; j < 4; ++j)
          ex[row * ESTR + wc * 64 + j * 16 + l15] = (_Float16)(acc[i][j][r] * omul);
      }
    __syncthreads();

    const int hl = isq ? bx : bx - NH;
    _Float16* dst0 = isq ? Qpk : Kpk;
#pragma unroll
    for (int u = 0; u < 2; ++u) {
      const int qtl = wv * 2 + u;
#pragma unroll
      for (int ds = 0; ds < 4; ++ds) {
        const f16x8 frag = *(const f16x8*)(ex + (qtl * 16 + l15) * ESTR + ds * 32 + l4 * 8);
        *(f16x8*)(dst0 + ((size_t)(hl * 128 + by * 8 + qtl) * 4 + ds) * 512 + lane * 8) = frag;
      }
    }
  } else {
    // ---- v head: cast + transpose to Vpk B-operand layout ----
    const int kvh = bx - NH - NKV;
#pragma unroll
    for (int i = 0; i < RT; ++i)
#pragma unroll
      for (int r = 0; r < 4; ++r) {
        const int row = wr * 64 + i * 16 + l4 * 4 + r;
#pragma unroll
        for (int j = 0; j < 4; ++j)
          ex[row * ESTR + wc * 64 + j * 16 + l15] = (_Float16)acc[i][j][r];
      }
    __syncthreads();
#pragma unroll
    for (int u = 0; u < 8; ++u) {
      const int idx = wv + 4 * u;          // 0..31
      const int dt = idx & 7, ks = (idx >> 3) & 1, ktl = idx >> 4;
      f16x8 h8;
#pragma unroll
      for (int jj = 0; jj < 8; ++jj)
        h8[jj] = ex[(ktl * 64 + ks * 32 + l4 * 8 + jj) * ESTR + dt * 16 + l15];
      *(f16x8*)(Vpk + (((size_t)(kvh * 32 + by * 2 + ktl) * 2 + ks) * 8 + dt) * 512 + lane * 8) = h8;
    }
  }
}

// ---------------------------------------------------------------------------
// fp16 MFMA GEMM (validated R4/R5) for the output projection, split-K.
// ---------------------------------------------------------------------------
template<int BN>
__global__ __launch_bounds__(256)
void gemm_f16(const _Float16* __restrict__ Apk, const _Float16* __restrict__ Bpk,
              float* __restrict__ C0, float* __restrict__ C1,
              int M, int N, int nkt) {
  constexpr int BM = 128;
  constexpr int AT = BM / 16;
  constexpr int BT = BN / 16;
  constexpr int RT = 4;
  constexpr int CT = BN / 32;
  __shared__ _Float16 As[2 * AT * 512];
  __shared__ _Float16 Bs[2 * BT * 512];

  const int tid = threadIdx.x;
  const int lane = tid & 63;
  const int wv = tid >> 6;
  const int wr = wv & 1, wc = wv >> 1;
  const int kt0 = blockIdx.z * nkt;
  float* __restrict__ C = blockIdx.z ? C1 : C0;

  f32x4 acc[RT][CT];
#pragma unroll
  for (int i = 0; i < RT; ++i)
#pragma unroll
    for (int j = 0; j < CT; ++j) acc[i][j] = (f32x4)0.f;

  const size_t Astep = (size_t)(M >> 4) * 1024;
  const size_t Bstep = (size_t)(N >> 4) * 1024;
  const char* Ag = (const char*)Apk + (size_t)kt0 * Astep +
                   (size_t)(blockIdx.y * AT) * 1024 + lane * 16;
  const char* Bg = (const char*)Bpk + (size_t)kt0 * Bstep +
                   (size_t)(blockIdx.x * BT) * 1024 + lane * 16;

  for (int kt2 = 0; kt2 < nkt; kt2 += 2) {
    const char* a0 = Ag + (size_t)kt2 * Astep;
    const char* b0 = Bg + (size_t)kt2 * Bstep;
#pragma unroll
    for (int t = wv; t < 2 * (AT + BT); t += 4) {
      const int half = t >= (AT + BT);
      const int tt = half ? t - (AT + BT) : t;
      if (tt < AT)
        gl2lds16(a0 + half * Astep + (size_t)tt * 1024,
                 (char*)As + (half * AT + tt) * 1024);
      else
        gl2lds16(b0 + half * Bstep + (size_t)(tt - AT) * 1024,
                 (char*)Bs + (half * BT + (tt - AT)) * 1024);
    }
    __syncthreads();

#pragma unroll
    for (int h2 = 0; h2 < 2; ++h2) {
      f16x8 af[RT], bf[CT];
#pragma unroll
      for (int i = 0; i < RT; ++i)
        af[i] = *(const f16x8*)((const char*)As + (h2 * AT + wr * RT + i) * 1024 + lane * 16);
#pragma unroll
      for (int j = 0; j < CT; ++j)
        bf[j] = *(const f16x8*)((const char*)Bs + (h2 * BT + wc * CT + j) * 1024 + lane * 16);
#pragma unroll
      for (int i = 0; i < RT; ++i)
#pragma unroll
        for (int j = 0; j < CT; ++j)
          acc[i][j] = __builtin_amdgcn_mfma_f32_16x16x32_f16(af[i], bf[j], acc[i][j], 0, 0, 0);
    }
    __syncthreads();
  }

  const int row0 = blockIdx.y * BM + wr * 64 + ((lane >> 4) << 2);
  const int col0 = blockIdx.x * BN + wc * (CT * 16) + (lane & 15);
#pragma unroll
  for (int i = 0; i < RT; ++i)
#pragma unroll
    for (int j = 0; j < CT; ++j) {
#pragma unroll
      for (int r = 0; r < 4; ++r)
        C[(size_t)(row0 + i * 16 + r) * N + col0 + j * 16] = acc[i][j][r];
    }
}

__global__ __launch_bounds__(256)
void reduce_add(const float4* __restrict__ a, const float4* __restrict__ b,
                float4* __restrict__ o, int n4) {
  for (int i = blockIdx.x * 256 + threadIdx.x; i < n4; i += gridDim.x * 256) {
    const float4 x = a[i], y = b[i];
    o[i] = make_float4(x.x + y.x, x.y + y.y, x.z + y.z, x.w + y.w);
  }
}

__global__ __launch_bounds__(64)
void rope_tables(const int* __restrict__ positions,
                 float* __restrict__ cosT, float* __restrict__ sinT) {
  const int j = threadIdx.x;
  const int p0 = blockIdx.x * 64;
  const float invf = (float)pow(1.0e6, -(double)j / 64.0);
#pragma unroll 4
  for (int i = 0; i < 64; ++i) {
    const int t = p0 + i;
    const float ang = (float)positions[t] * invf;
    cosT[t * 64 + j] = cosf(ang);
    sinT[t * 64 + j] = sinf(ang);
  }
}

// ---------------------------------------------------------------------------
// MFMA flash attention, static-max softmax (validated R5).
// ---------------------------------------------------------------------------
__global__ __launch_bounds__(256)
void attn_mfma(const _Float16* __restrict__ Qpk, const _Float16* __restrict__ Kpk,
               const _Float16* __restrict__ Vpk, _Float16* __restrict__ Ap2) {
  const int h = blockIdx.x;
  const int q0 = blockIdx.y * 128;
  const int kvh = h >> 3;
  const int tid = threadIdx.x;
  const int lane = tid & 63;
  const int wv = tid >> 6;
  const int l15 = lane & 15;
  const int l4 = lane >> 4;

  __shared__ _Float16 SM[8192 + 8192 + 4 * 32 * PSTR];
  _Float16* Ks = SM;
  _Float16* Vs = SM + 8192;
  _Float16* Pw = SM + 16384 + wv * 32 * PSTR;

  f16x8 qfA[4], qfB[4];
  {
    const _Float16* qa = Qpk + ((size_t)h * 128 + (q0 >> 4) + wv * 2) * 2048 + lane * 8;
#pragma unroll
    for (int ds = 0; ds < 4; ++ds) {
      qfA[ds] = *(const f16x8*)(qa + ds * 512);
      qfB[ds] = *(const f16x8*)(qa + 2048 + ds * 512);
    }
  }

  f16x8 ones;
#pragma unroll
  for (int j = 0; j < 8; ++j) ones[j] = (_Float16)1.0f;

  f32x4 OA[8], OB[8];
#pragma unroll
  for (int dt = 0; dt < 8; ++dt) { OA[dt] = (f32x4)0.f; OB[dt] = (f32x4)0.f; }
  f32x4 LA = (f32x4)0.f, LB = (f32x4)0.f;

  int kstart = q0 - (WINDOW - 1);
  if (kstart < 0) kstart = 0;
  kstart &= ~63;

  for (int kt = kstart; kt < q0 + 128; kt += 64) {
    __syncthreads();
    const _Float16* Kg = Kpk + ((size_t)kvh * 128 + (kt >> 4)) * 2048 + lane * 8;
    const _Float16* Vg = Vpk + ((size_t)kvh * 32 + (kt >> 6)) * 8192 + lane * 8;
#pragma unroll
    for (int t = wv; t < 16; t += 4) {
      gl2lds16(Kg + t * 512, (char*)Ks + t * 1024);
      gl2lds16(Vg + t * 512, (char*)Vs + t * 1024);
    }
    __syncthreads();

    f32x4 sA[4], sB[4];
#pragma unroll
    for (int nt = 0; nt < 4; ++nt) { sA[nt] = (f32x4)(-MLOG2E); sB[nt] = (f32x4)(-MLOG2E); }
#pragma unroll
    for (int ds = 0; ds < 4; ++ds) {
#pragma unroll
      for (int nt = 0; nt < 4; ++nt) {
        const f16x8 kf = *(const f16x8*)(Ks + (nt * 4 + ds) * 512 + lane * 8);
        sA[nt] = __builtin_amdgcn_mfma_f32_16x16x32_f16(qfA[ds], kf, sA[nt], 0, 0, 0);
        sB[nt] = __builtin_amdgcn_mfma_f32_16x16x32_f16(qfB[ds], kf, sB[nt], 0, 0, 0);
      }
    }

    const int qbA = q0 + wv * 32 + l4 * 4;
    const int kb = kt + l15;
#pragma unroll
    for (int nt = 0; nt < 4; ++nt) {
      const int kidx = kb + nt * 16;
#pragma unroll
      for (int r = 0; r < 4; ++r) {
        float pA = __builtin_amdgcn_exp2f(sA[nt][r]);
        float pB = __builtin_amdgcn_exp2f(sB[nt][r]);
        pA = ((unsigned)(qbA + r - kidx) < WINDOW) ? pA : 0.f;
        pB = ((unsigned)(qbA + 16 + r - kidx) < WINDOW) ? pB : 0.f;
        Pw[(l4 * 4 + r) * PSTR + nt * 16 + l15] = (_Float16)pA;
        Pw[(16 + l4 * 4 + r) * PSTR + nt * 16 + l15] = (_Float16)pB;
      }
    }

#pragma unroll
    for (int ks = 0; ks < 2; ++ks) {
      const f16x8 pfA = *(const f16x8*)(Pw + l15 * PSTR + ks * 32 + l4 * 8);
      const f16x8 pfB = *(const f16x8*)(Pw + (16 + l15) * PSTR + ks * 32 + l4 * 8);
      LA = __builtin_amdgcn_mfma_f32_16x16x32_f16(pfA, ones, LA, 0, 0, 0);
      LB = __builtin_amdgcn_mfma_f32_16x16x32_f16(pfB, ones, LB, 0, 0, 0);
#pragma unroll
      for (int dt = 0; dt < 8; ++dt) {
        const f16x8 vf = *(const f16x8*)(Vs + (ks * 8 + dt) * 512 + lane * 8);
        OA[dt] = __builtin_amdgcn_mfma_f32_16x16x32_f16(pfA, vf, OA[dt], 0, 0, 0);
        OB[dt] = __builtin_amdgcn_mfma_f32_16x16x32_f16(pfB, vf, OB[dt], 0, 0, 0);
      }
    }
  }

  __syncthreads();
  _Float16* Tw = SM + wv * 16 * ESTR;
#pragma unroll
  for (int half = 0; half < 2; ++half) {
    const f32x4* O = half ? OB : OA;
    const f32x4  L = half ? LB : LA;
    float inv[4];
#pragma unroll
    for (int r = 0; r < 4; ++r) inv[r] = 1.0f / L[r];
#pragma unroll
    for (int dt = 0; dt < 8; ++dt)
#pragma unroll
      for (int r = 0; r < 4; ++r)
        Tw[(l4 * 4 + r) * ESTR + dt * 16 + l15] = (_Float16)(O[dt][r] * inv[r]);
    const int qt = (q0 >> 4) + wv * 2 + half;
#pragma unroll
    for (int ds = 0; ds < 4; ++ds) {
      const f16x8 frag = *(const f16x8*)(Tw + l15 * ESTR + ds * 32 + l4 * 8);
      *(f16x8*)(Ap2 + ((size_t)(h * 4 + ds) * 128 + qt) * 512 + lane * 8) = frag;
    }
  }
}

// ---------------------------------------------------------------------------
// Launch
// ---------------------------------------------------------------------------
extern "C" void kernel_launch(void* const* d_in, const int* in_sizes, int n_in,
                              void* d_out, int out_size, void* d_ws, size_t ws_size,
                              hipStream_t stream) {
  const int*   positions = (const int*)d_in[0];
  const float* hidden    = (const float*)d_in[1];
  const float* w_qkv     = (const float*)d_in[2];
  const float* w_o       = (const float*)d_in[3];
  const float* q_norm_w  = (const float*)d_in[4];
  const float* k_norm_w  = (const float*)d_in[5];
  float* out = (float*)d_out;

  // workspace (same 139.5 MB footprint; old qkv region now hosts Kpk/Vpk)
  char* ws = (char*)d_ws;
  _Float16* Kpk = (_Float16*)ws;                    // 2.1 MB
  _Float16* Vpk = Kpk + (size_t)T * NKV * D;        // 2.1 MB
  ws += (size_t)T * QKVW * 4;                       // (rest of old qkv region free)
  _Float16* Ap2 = (_Float16*)ws;                    // 16.8 MB
  float* P0 = (float*)(ws + (size_t)T * ODIM * 2);  // 16.8 MB
  ws += (size_t)T * ODIM * 4;
  float* cosT = (float*)ws;  ws += (size_t)T * 64 * 4;
  float* sinT = (float*)ws;  ws += (size_t)T * 64 * 4;
  _Float16* Bp1 = (_Float16*)ws; ws += (size_t)HIDDEN * QKVW * 2;  // 21.0 MB
  _Float16* Bp2 = (_Float16*)ws; ws += (size_t)ODIM * HIDDEN * 2;  // 16.8 MB
  _Float16* Ah1 = (_Float16*)ws; ws += (size_t)T * HIDDEN * 2;     // 8.4 MB
  _Float16* Qpk = (_Float16*)ws;                    // 16.8 MB (dead after attn)
  float* P1 = (float*)Qpk;                          // alias: written after attn
  ws += (size_t)T * ODIM * 2;

  // operand packs + RoPE tables (tables must precede gemm_qkv)
  pack_a<<<dim3((size_t)T * HIDDEN / 8 / 256), 256, 0, stream>>>(hidden, Ah1, T, HIDDEN);
  pack_b<<<dim3((size_t)HIDDEN * QKVW / 8 / 256), 256, 0, stream>>>(w_qkv, Bp1, HIDDEN, QKVW);
  pack_b<<<dim3((size_t)ODIM * HIDDEN / 8 / 256), 256, 0, stream>>>(w_o, Bp2, ODIM, HIDDEN);
  rope_tables<<<dim3(T / 64), 64, 0, stream>>>(positions, cosT, sinT);

  // 1) fused qkv GEMM + RMSNorm/RoPE/pack -> Qpk, Kpk, Vpk
  gemm_qkv<<<dim3(QKVW / 128, T / 128), 256, 0, stream>>>(
      Ah1, Bp1, q_norm_w, k_norm_w, cosT, sinT, Qpk, Kpk, Vpk);

  // 2) MFMA flash attention -> Ap2 (gemm2 A-operand)
  attn_mfma<<<dim3(NH, T / 128), 256, 0, stream>>>(Qpk, Kpk, Vpk, Ap2);

  // 3) out = attn @ w_o, split-K=2, then reduce
  gemm_f16<128><<<dim3(HIDDEN / 128, T / 128, 2), 256, 0, stream>>>(
      Ap2, Bp2, P0, P1, T, HIDDEN, ODIM / 32 / 2);
  reduce_add<<<dim3(512), 256, 0, stream>>>((const float4*)P0, (const float4*)P1,
                                            (float4*)out, T * HIDDEN / 4);
}

// Round 7
// 296.286 us; speedup vs baseline: 1.0923x; 1.0923x over previous
//
#include <hip/hip_runtime.h>
#include <math.h>

// Problem constants
#define T      2048
#define HIDDEN 2048
#define NH     32
#define NKV    4
#define D      128
#define WINDOW 512
#define QKVW   ((NH + 2 * NKV) * D)   // 5120
#define ODIM   (NH * D)               // 4096
#define EPS    1e-6f
#define SCALE  0.08838834764831845f   // D^-0.5
#define PSTR   68                     // attn P-slab stride (validated R5)
#define ESTR   136                    // Q/K epilogue slab stride (16B-aligned rows)
#define VSTR   36                     // V epilogue slab stride (8B-aligned)
#define QMUL   ((float)(0.08838834764831845 * 1.4426950408889634))
#define MLOG2E 5.7707801635558536f    // 4.0*log2(e); |score|<=11.3 (Cauchy-Schwarz)

typedef _Float16 f16x8 __attribute__((ext_vector_type(8)));
typedef _Float16 f16x4 __attribute__((ext_vector_type(4)));
typedef float    f32x4 __attribute__((ext_vector_type(4)));

// ---------------------------------------------------------------------------
// Packed fragment format (validated R2-R6):
// chunk c = q*16 + o (q=c>>4, o=c&15), chunk = 8 k-consecutive f16 at outer o.
// A-operand: lane holds A[m=lane&15][k=(lane>>4)*8+j]
// B-operand: lane holds B[k=(lane>>4)*8+j][n=lane&15]
// ---------------------------------------------------------------------------

__device__ __forceinline__ void gl2lds16(const void* g, void* l) {
  __builtin_amdgcn_global_load_lds((const __attribute__((address_space(1))) void*)g,
                                   (__attribute__((address_space(3))) void*)l,
                                   16, 0, 0);
}

// ---------------------------------------------------------------------------
// prep: all input packing + RoPE tables in ONE dispatch (block-range branch).
//   [0, 2048)            pack_a(hidden -> Ah1)
//   [2048, 7168)         pack_b(w_qkv -> Bp1)
//   [7168, 11264)        pack_b(w_o -> Bp2)
//   [11264, 11296)       rope tables
// ---------------------------------------------------------------------------
#define NB_A  2048
#define NB_B1 5120
#define NB_B2 4096
__global__ __launch_bounds__(256)
void prep(const float* __restrict__ hidden, const float* __restrict__ w_qkv,
          const float* __restrict__ w_o, const int* __restrict__ positions,
          _Float16* __restrict__ Ah1, _Float16* __restrict__ Bp1,
          _Float16* __restrict__ Bp2, float* __restrict__ cosT,
          float* __restrict__ sinT) {
  const int bx = blockIdx.x;
  const int tid = threadIdx.x;
  if (bx < NB_A) {
    // pack A: hidden [T][HIDDEN] -> A-frag chunks
    const int cid = bx * 256 + tid;
    const int c = cid & 63;
    const int tile = cid >> 6;
    const int mtg = tile & (T / 16 - 1);
    const int kt = tile >> 7;
    const float* src = hidden + (size_t)(mtg * 16 + (c & 15)) * HIDDEN + kt * 32 + (c >> 4) * 8;
    const float4 a = *(const float4*)src;
    const float4 b = *(const float4*)(src + 4);
    f16x8 h;
    h[0] = (_Float16)a.x; h[1] = (_Float16)a.y; h[2] = (_Float16)a.z; h[3] = (_Float16)a.w;
    h[4] = (_Float16)b.x; h[5] = (_Float16)b.y; h[6] = (_Float16)b.z; h[7] = (_Float16)b.w;
    *(f16x8*)(Ah1 + (size_t)cid * 8) = h;
  } else if (bx < NB_A + NB_B1) {
    // pack B: w_qkv [HIDDEN][QKVW]
    const int cid = (bx - NB_A) * 256 + tid;
    const int c = cid & 63;
    const int tile = cid >> 6;
    const int ntg = tile % (QKVW >> 4);
    const int kt = tile / (QKVW >> 4);
    const float* src = w_qkv + (size_t)(kt * 32 + (c >> 4) * 8) * QKVW + ntg * 16 + (c & 15);
    f16x8 h;
#pragma unroll
    for (int j = 0; j < 8; ++j) h[j] = (_Float16)src[(size_t)j * QKVW];
    *(f16x8*)(Bp1 + (size_t)cid * 8) = h;
  } else if (bx < NB_A + NB_B1 + NB_B2) {
    // pack B: w_o [ODIM][HIDDEN]
    const int cid = (bx - NB_A - NB_B1) * 256 + tid;
    const int c = cid & 63;
    const int tile = cid >> 6;
    const int ntg = tile & (HIDDEN / 16 - 1);
    const int kt = tile >> 7;
    const float* src = w_o + (size_t)(kt * 32 + (c >> 4) * 8) * HIDDEN + ntg * 16 + (c & 15);
    f16x8 h;
#pragma unroll
    for (int j = 0; j < 8; ++j) h[j] = (_Float16)src[(size_t)j * HIDDEN];
    *(f16x8*)(Bp2 + (size_t)cid * 8) = h;
  } else {
    // RoPE tables: 64 positions per block
    const int p0 = (bx - NB_A - NB_B1 - NB_B2) * 64 + (tid >> 6) * 16;
    const int j = tid & 63;
    const float invf = (float)pow(1.0e6, -(double)j / 64.0);
#pragma unroll 4
    for (int i = 0; i < 16; ++i) {
      const int t = p0 + i;
      const float ang = (float)positions[t] * invf;
      cosT[t * 64 + j] = cosf(ang);
      sinT[t * 64 + j] = sinf(ang);
    }
  }
}

// ---------------------------------------------------------------------------
// gemm1 fused: qkv = hidden @ w_qkv with RMSNorm+RoPE+pack epilogue.
// Wave tiling 1x4: each wave owns 32 rows x 128 cols (acc[2][8]) so the
// RoPE partner col^64 = acc[i][j^4][r] is IN-REGISTER and the epilogue is
// barrier-free (wave-private LDS slabs only).
// bx<32: q head -> Qpk ; 32..35: k -> Kpk ; 36..39: v -> Vpk.
// ---------------------------------------------------------------------------
__global__ __launch_bounds__(256)
void gemm_qkv(const _Float16* __restrict__ Apk, const _Float16* __restrict__ Bpk,
              const float* __restrict__ qnw, const float* __restrict__ knw,
              const float* __restrict__ cosT, const float* __restrict__ sinT,
              _Float16* __restrict__ Qpk, _Float16* __restrict__ Kpk,
              _Float16* __restrict__ Vpk) {
  constexpr int NKT = HIDDEN / 32;     // 64
  __shared__ _Float16 SM[18432];       // 36864 B: staging(32KB) U epilogue slabs
  _Float16* As = SM;                   // [2 halves][8 tiles][512]
  _Float16* Bs = SM + 8192;

  const int tid = threadIdx.x;
  const int lane = tid & 63;
  const int wv = tid >> 6;
  const int l15 = lane & 15;
  const int l4 = lane >> 4;
  const int bx = blockIdx.x, by = blockIdx.y;

  f32x4 acc[2][8];
#pragma unroll
  for (int i = 0; i < 2; ++i)
#pragma unroll
    for (int j = 0; j < 8; ++j) acc[i][j] = (f32x4)0.f;

  const size_t Astep = (size_t)(T >> 4) * 1024;
  const size_t Bstep = (size_t)(QKVW >> 4) * 1024;
  const char* Ag = (const char*)Apk + (size_t)(by * 8) * 1024 + lane * 16;
  const char* Bg = (const char*)Bpk + (size_t)(bx * 8) * 1024 + lane * 16;

  for (int kt2 = 0; kt2 < NKT; kt2 += 2) {
    const char* a0 = Ag + (size_t)kt2 * Astep;
    const char* b0 = Bg + (size_t)kt2 * Bstep;
#pragma unroll
    for (int t = wv; t < 32; t += 4) {
      const int half = t >= 16;
      const int tt = half ? t - 16 : t;
      if (tt < 8)
        gl2lds16(a0 + half * Astep + (size_t)tt * 1024,
                 (char*)As + (half * 8 + tt) * 1024);
      else
        gl2lds16(b0 + half * Bstep + (size_t)(tt - 8) * 1024,
                 (char*)Bs + (half * 8 + (tt - 8)) * 1024);
    }
    __syncthreads();
#pragma unroll
    for (int h2 = 0; h2 < 2; ++h2) {
      f16x8 af[2], bf[8];
#pragma unroll
      for (int i = 0; i < 2; ++i)
        af[i] = *(const f16x8*)(As + (h2 * 8 + wv * 2 + i) * 512 + lane * 8);
#pragma unroll
      for (int j = 0; j < 8; ++j)
        bf[j] = *(const f16x8*)(Bs + (h2 * 8 + j) * 512 + lane * 8);
#pragma unroll
      for (int i = 0; i < 2; ++i)
#pragma unroll
        for (int j = 0; j < 8; ++j)
          acc[i][j] = __builtin_amdgcn_mfma_f32_16x16x32_f16(af[i], bf[j], acc[i][j], 0, 0, 0);
    }
    __syncthreads();   // last barrier also fences staging before epilogue
  }

  // ---- barrier-free fused epilogue ----
  // acc[i][j][r] = C[row][col], row(local) = i*16+l4*4+r (wave rows 0..31),
  // col = j*16+l15. Wave's global rows = by*128 + wv*32 + local.
  if (bx < NH + NKV) {
    const bool isq = bx < NH;
    const float* w = isq ? qnw : knw;
    const float omul = isq ? QMUL : 1.0f;
    float wcol[8];
#pragma unroll
    for (int j = 0; j < 8; ++j) wcol[j] = w[j * 16 + l15];

    _Float16* ex = SM + wv * (32 * ESTR);   // wave-private 32 x 136
#pragma unroll
    for (int i = 0; i < 2; ++i)
#pragma unroll
      for (int r = 0; r < 4; ++r) {
        float ss = 0.f;
#pragma unroll
        for (int j = 0; j < 8; ++j) ss += acc[i][j][r] * acc[i][j][r];
        ss += __shfl_xor(ss, 1); ss += __shfl_xor(ss, 2);
        ss += __shfl_xor(ss, 4); ss += __shfl_xor(ss, 8);
        const float rn = 1.0f / sqrtf(ss * (1.0f / D) + EPS);
        const int row = i * 16 + l4 * 4 + r;
        const int t = by * 128 + wv * 32 + row;
#pragma unroll
        for (int j = 0; j < 4; ++j) {
          const int jc = j * 16 + l15;
          const float c = cosT[t * 64 + jc];
          const float s = sinT[t * 64 + jc];
          const float x1 = acc[i][j][r] * rn * wcol[j];
          const float x2 = acc[i][j + 4][r] * rn * wcol[j + 4];
          ex[row * ESTR + jc]      = (_Float16)((x1 * c - x2 * s) * omul);
          ex[row * ESTR + 64 + jc] = (_Float16)((x2 * c + x1 * s) * omul);
        }
      }
    // read back in A-frag order (in-wave lgkmcnt ordering, no barrier)
    const int hl = isq ? bx : bx - NH;
    _Float16* dst0 = isq ? Qpk : Kpk;
#pragma unroll
    for (int u = 0; u < 2; ++u) {
      const int qt = by * 8 + wv * 2 + u;
#pragma unroll
      for (int ds = 0; ds < 4; ++ds) {
        const f16x8 frag = *(const f16x8*)(ex + (u * 16 + l15) * ESTR + ds * 32 + l4 * 8);
        *(f16x8*)(dst0 + ((size_t)(hl * 128 + qt) * 4 + ds) * 512 + lane * 8) = frag;
      }
    }
  } else {
    // V: cast + transpose to validated Vpk B-operand layout, wave-private
    const int kvh = bx - NH - NKV;
    _Float16* exv = SM + wv * (128 * VSTR);  // [d 0..127][local key 0..31]
#pragma unroll
    for (int i = 0; i < 2; ++i)
#pragma unroll
      for (int j = 0; j < 8; ++j) {
        f16x4 v4;
#pragma unroll
        for (int r = 0; r < 4; ++r) v4[r] = (_Float16)acc[i][j][r];
        *(f16x4*)(exv + (j * 16 + l15) * VSTR + i * 16 + l4 * 4) = v4;
      }
    const int kt64 = by * 2 + (wv >> 1);
    const int ks = wv & 1;
#pragma unroll
    for (int dt = 0; dt < 8; ++dt) {
      const f16x4 lo = *(const f16x4*)(exv + (dt * 16 + l15) * VSTR + l4 * 8);
      const f16x4 hi = *(const f16x4*)(exv + (dt * 16 + l15) * VSTR + l4 * 8 + 4);
      f16x8 h8;
#pragma unroll
      for (int r = 0; r < 4; ++r) { h8[r] = lo[r]; h8[r + 4] = hi[r]; }
      *(f16x8*)(Vpk + (((size_t)(kvh * 32 + kt64) * 2 + ks) * 8 + dt) * 512 + lane * 8) = h8;
    }
  }
}

// ---------------------------------------------------------------------------
// fp16 MFMA GEMM (validated R4-R6) for the output projection, split-K.
// ---------------------------------------------------------------------------
template<int BN>
__global__ __launch_bounds__(256)
void gemm_f16(const _Float16* __restrict__ Apk, const _Float16* __restrict__ Bpk,
              float* __restrict__ C0, float* __restrict__ C1,
              int M, int N, int nkt) {
  constexpr int BM = 128;
  constexpr int AT = BM / 16;
  constexpr int BT = BN / 16;
  constexpr int RT = 4;
  constexpr int CT = BN / 32;
  __shared__ _Float16 As[2 * AT * 512];
  __shared__ _Float16 Bs[2 * BT * 512];

  const int tid = threadIdx.x;
  const int lane = tid & 63;
  const int wv = tid >> 6;
  const int wr = wv & 1, wc = wv >> 1;
  const int kt0 = blockIdx.z * nkt;
  float* __restrict__ C = blockIdx.z ? C1 : C0;

  f32x4 acc[RT][CT];
#pragma unroll
  for (int i = 0; i < RT; ++i)
#pragma unroll
    for (int j = 0; j < CT; ++j) acc[i][j] = (f32x4)0.f;

  const size_t Astep = (size_t)(M >> 4) * 1024;
  const size_t Bstep = (size_t)(N >> 4) * 1024;
  const char* Ag = (const char*)Apk + (size_t)kt0 * Astep +
                   (size_t)(blockIdx.y * AT) * 1024 + lane * 16;
  const char* Bg = (const char*)Bpk + (size_t)kt0 * Bstep +
                   (size_t)(blockIdx.x * BT) * 1024 + lane * 16;

  for (int kt2 = 0; kt2 < nkt; kt2 += 2) {
    const char* a0 = Ag + (size_t)kt2 * Astep;
    const char* b0 = Bg + (size_t)kt2 * Bstep;
#pragma unroll
    for (int t = wv; t < 2 * (AT + BT); t += 4) {
      const int half = t >= (AT + BT);
      const int tt = half ? t - (AT + BT) : t;
      if (tt < AT)
        gl2lds16(a0 + half * Astep + (size_t)tt * 1024,
                 (char*)As + (half * AT + tt) * 1024);
      else
        gl2lds16(b0 + half * Bstep + (size_t)(tt - AT) * 1024,
                 (char*)Bs + (half * BT + (tt - AT)) * 1024);
    }
    __syncthreads();

#pragma unroll
    for (int h2 = 0; h2 < 2; ++h2) {
      f16x8 af[RT], bf[CT];
#pragma unroll
      for (int i = 0; i < RT; ++i)
        af[i] = *(const f16x8*)((const char*)As + (h2 * AT + wr * RT + i) * 1024 + lane * 16);
#pragma unroll
      for (int j = 0; j < CT; ++j)
        bf[j] = *(const f16x8*)((const char*)Bs + (h2 * BT + wc * CT + j) * 1024 + lane * 16);
#pragma unroll
      for (int i = 0; i < RT; ++i)
#pragma unroll
        for (int j = 0; j < CT; ++j)
          acc[i][j] = __builtin_amdgcn_mfma_f32_16x16x32_f16(af[i], bf[j], acc[i][j], 0, 0, 0);
    }
    __syncthreads();
  }

  const int row0 = blockIdx.y * BM + wr * 64 + ((lane >> 4) << 2);
  const int col0 = blockIdx.x * BN + wc * (CT * 16) + (lane & 15);
#pragma unroll
  for (int i = 0; i < RT; ++i)
#pragma unroll
    for (int j = 0; j < CT; ++j) {
#pragma unroll
      for (int r = 0; r < 4; ++r)
        C[(size_t)(row0 + i * 16 + r) * N + col0 + j * 16] = acc[i][j][r];
    }
}

__global__ __launch_bounds__(256)
void reduce_add(const float4* __restrict__ a, const float4* __restrict__ b,
                float4* __restrict__ o, int n4) {
  for (int i = blockIdx.x * 256 + threadIdx.x; i < n4; i += gridDim.x * 256) {
    const float4 x = a[i], y = b[i];
    o[i] = make_float4(x.x + y.x, x.y + y.y, x.z + y.z, x.w + y.w);
  }
}

// ---------------------------------------------------------------------------
// MFMA flash attention, static-max softmax (validated R5/R6).
// ---------------------------------------------------------------------------
__global__ __launch_bounds__(256)
void attn_mfma(const _Float16* __restrict__ Qpk, const _Float16* __restrict__ Kpk,
               const _Float16* __restrict__ Vpk, _Float16* __restrict__ Ap2) {
  const int h = blockIdx.x;
  const int q0 = blockIdx.y * 128;
  const int kvh = h >> 3;
  const int tid = threadIdx.x;
  const int lane = tid & 63;
  const int wv = tid >> 6;
  const int l15 = lane & 15;
  const int l4 = lane >> 4;

  __shared__ _Float16 SM[8192 + 8192 + 4 * 32 * PSTR];
  _Float16* Ks = SM;
  _Float16* Vs = SM + 8192;
  _Float16* Pw = SM + 16384 + wv * 32 * PSTR;

  f16x8 qfA[4], qfB[4];
  {
    const _Float16* qa = Qpk + ((size_t)h * 128 + (q0 >> 4) + wv * 2) * 2048 + lane * 8;
#pragma unroll
    for (int ds = 0; ds < 4; ++ds) {
      qfA[ds] = *(const f16x8*)(qa + ds * 512);
      qfB[ds] = *(const f16x8*)(qa + 2048 + ds * 512);
    }
  }

  f16x8 ones;
#pragma unroll
  for (int j = 0; j < 8; ++j) ones[j] = (_Float16)1.0f;

  f32x4 OA[8], OB[8];
#pragma unroll
  for (int dt = 0; dt < 8; ++dt) { OA[dt] = (f32x4)0.f; OB[dt] = (f32x4)0.f; }
  f32x4 LA = (f32x4)0.f, LB = (f32x4)0.f;

  int kstart = q0 - (WINDOW - 1);
  if (kstart < 0) kstart = 0;
  kstart &= ~63;

  for (int kt = kstart; kt < q0 + 128; kt += 64) {
    __syncthreads();
    const _Float16* Kg = Kpk + ((size_t)kvh * 128 + (kt >> 4)) * 2048 + lane * 8;
    const _Float16* Vg = Vpk + ((size_t)kvh * 32 + (kt >> 6)) * 8192 + lane * 8;
#pragma unroll
    for (int t = wv; t < 16; t += 4) {
      gl2lds16(Kg + t * 512, (char*)Ks + t * 1024);
      gl2lds16(Vg + t * 512, (char*)Vs + t * 1024);
    }
    __syncthreads();

    f32x4 sA[4], sB[4];
#pragma unroll
    for (int nt = 0; nt < 4; ++nt) { sA[nt] = (f32x4)(-MLOG2E); sB[nt] = (f32x4)(-MLOG2E); }
#pragma unroll
    for (int ds = 0; ds < 4; ++ds) {
#pragma unroll
      for (int nt = 0; nt < 4; ++nt) {
        const f16x8 kf = *(const f16x8*)(Ks + (nt * 4 + ds) * 512 + lane * 8);
        sA[nt] = __builtin_amdgcn_mfma_f32_16x16x32_f16(qfA[ds], kf, sA[nt], 0, 0, 0);
        sB[nt] = __builtin_amdgcn_mfma_f32_16x16x32_f16(qfB[ds], kf, sB[nt], 0, 0, 0);
      }
    }

    const int qbA = q0 + wv * 32 + l4 * 4;
    const int kb = kt + l15;
#pragma unroll
    for (int nt = 0; nt < 4; ++nt) {
      const int kidx = kb + nt * 16;
#pragma unroll
      for (int r = 0; r < 4; ++r) {
        float pA = __builtin_amdgcn_exp2f(sA[nt][r]);
        float pB = __builtin_amdgcn_exp2f(sB[nt][r]);
        pA = ((unsigned)(qbA + r - kidx) < WINDOW) ? pA : 0.f;
        pB = ((unsigned)(qbA + 16 + r - kidx) < WINDOW) ? pB : 0.f;
        Pw[(l4 * 4 + r) * PSTR + nt * 16 + l15] = (_Float16)pA;
        Pw[(16 + l4 * 4 + r) * PSTR + nt * 16 + l15] = (_Float16)pB;
      }
    }

#pragma unroll
    for (int ks = 0; ks < 2; ++ks) {
      const f16x8 pfA = *(const f16x8*)(Pw + l15 * PSTR + ks * 32 + l4 * 8);
      const f16x8 pfB = *(const f16x8*)(Pw + (16 + l15) * PSTR + ks * 32 + l4 * 8);
      LA = __builtin_amdgcn_mfma_f32_16x16x32_f16(pfA, ones, LA, 0, 0, 0);
      LB = __builtin_amdgcn_mfma_f32_16x16x32_f16(pfB, ones, LB, 0, 0, 0);
#pragma unroll
      for (int dt = 0; dt < 8; ++dt) {
        const f16x8 vf = *(const f16x8*)(Vs + (ks * 8 + dt) * 512 + lane * 8);
        OA[dt] = __builtin_amdgcn_mfma_f32_16x16x32_f16(pfA, vf, OA[dt], 0, 0, 0);
        OB[dt] = __builtin_amdgcn_mfma_f32_16x16x32_f16(pfB, vf, OB[dt], 0, 0, 0);
      }
    }
  }

  __syncthreads();
  _Float16* Tw = SM + wv * 16 * ESTR;
#pragma unroll
  for (int half = 0; half < 2; ++half) {
    const f32x4* O = half ? OB : OA;
    const f32x4  L = half ? LB : LA;
    float inv[4];
#pragma unroll
    for (int r = 0; r < 4; ++r) inv[r] = 1.0f / L[r];
#pragma unroll
    for (int dt = 0; dt < 8; ++dt)
#pragma unroll
      for (int r = 0; r < 4; ++r)
        Tw[(l4 * 4 + r) * ESTR + dt * 16 + l15] = (_Float16)(O[dt][r] * inv[r]);
    const int qt = (q0 >> 4) + wv * 2 + half;
#pragma unroll
    for (int ds = 0; ds < 4; ++ds) {
      const f16x8 frag = *(const f16x8*)(Tw + l15 * ESTR + ds * 32 + l4 * 8);
      *(f16x8*)(Ap2 + ((size_t)(h * 4 + ds) * 128 + qt) * 512 + lane * 8) = frag;
    }
  }
}

// ---------------------------------------------------------------------------
// Launch (5 dispatches)
// ---------------------------------------------------------------------------
extern "C" void kernel_launch(void* const* d_in, const int* in_sizes, int n_in,
                              void* d_out, int out_size, void* d_ws, size_t ws_size,
                              hipStream_t stream) {
  const int*   positions = (const int*)d_in[0];
  const float* hidden    = (const float*)d_in[1];
  const float* w_qkv     = (const float*)d_in[2];
  const float* w_o       = (const float*)d_in[3];
  const float* q_norm_w  = (const float*)d_in[4];
  const float* k_norm_w  = (const float*)d_in[5];
  float* out = (float*)d_out;

  // workspace (same 139.5 MB footprint as R6)
  char* ws = (char*)d_ws;
  _Float16* Kpk = (_Float16*)ws;                    // 2.1 MB
  _Float16* Vpk = Kpk + (size_t)T * NKV * D;        // 2.1 MB
  ws += (size_t)T * QKVW * 4;
  _Float16* Ap2 = (_Float16*)ws;                    // 16.8 MB
  float* P0 = (float*)(ws + (size_t)T * ODIM * 2);  // 16.8 MB
  ws += (size_t)T * ODIM * 4;
  float* cosT = (float*)ws;  ws += (size_t)T * 64 * 4;
  float* sinT = (float*)ws;  ws += (size_t)T * 64 * 4;
  _Float16* Bp1 = (_Float16*)ws; ws += (size_t)HIDDEN * QKVW * 2;  // 21.0 MB
  _Float16* Bp2 = (_Float16*)ws; ws += (size_t)ODIM * HIDDEN * 2;  // 16.8 MB
  _Float16* Ah1 = (_Float16*)ws; ws += (size_t)T * HIDDEN * 2;     // 8.4 MB
  _Float16* Qpk = (_Float16*)ws;                    // dead after attn
  float* P1 = (float*)Qpk;                          // alias: written after attn
  ws += (size_t)T * ODIM * 2;

  // 0) all packing + RoPE tables in one dispatch
  prep<<<dim3(NB_A + NB_B1 + NB_B2 + T / 64), 256, 0, stream>>>(
      hidden, w_qkv, w_o, positions, Ah1, Bp1, Bp2, cosT, sinT);

  // 1) fused qkv GEMM + RMSNorm/RoPE/pack -> Qpk, Kpk, Vpk
  gemm_qkv<<<dim3(QKVW / 128, T / 128), 256, 0, stream>>>(
      Ah1, Bp1, q_norm_w, k_norm_w, cosT, sinT, Qpk, Kpk, Vpk);

  // 2) MFMA flash attention -> Ap2 (gemm2 A-operand)
  attn_mfma<<<dim3(NH, T / 128), 256, 0, stream>>>(Qpk, Kpk, Vpk, Ap2);

  // 3) out = attn @ w_o, split-K=2, then reduce
  gemm_f16<128><<<dim3(HIDDEN / 128, T / 128, 2), 256, 0, stream>>>(
      Ap2, Bp2, P0, P1, T, HIDDEN, ODIM / 32 / 2);
  reduce_add<<<dim3(512), 256, 0, stream>>>((const float4*)P0, (const float4*)P1,
                                            (float4*)out, T * HIDDEN / 4);
}